// Round 3
// baseline (2511.004 us; speedup 1.0000x reference)
//
#include <hip/hip_runtime.h>
#include <math.h>

#define N_NODES 10000
#define N_EDGES 160000
#define NGRAPH  64
#define CDIM    512        // HEADS*HID
#define HEADS   4
#define HLDIM   768
#define GATE    (4*HLDIM)  // 3072
#define NEG     0.2f

typedef __attribute__((ext_vector_type(8))) short s8v;   // 8 bf16 = 4 VGPR (MFMA A/B frag)
typedef __attribute__((ext_vector_type(4))) float f4v;   // MFMA C/D frag

__device__ __forceinline__ float lrelu(float x){ return x > 0.f ? x : NEG * x; }
__device__ __forceinline__ float sigf (float x){ return 1.f / (1.f + expf(-x)); }

// RNE float->bf16 (finite data only) and exact bf16->float
__device__ __forceinline__ unsigned short f2bf(float f) {
    unsigned u = __float_as_uint(f);
    u += 0x7fffu + ((u >> 16) & 1u);
    return (unsigned short)(u >> 16);
}
__device__ __forceinline__ float bf2f(unsigned short h) {
    return __uint_as_float(((unsigned)h) << 16);
}

// ---------------------------------------------------------------------------
// split fp32 -> (bf16 hi, bf16 lo):  x ~= hi + lo, |lo| <~ 2^-9|x|, err ~ 2^-16
// n4 = n/4 (n multiple of 4)
// ---------------------------------------------------------------------------
__global__ __launch_bounds__(256) void split_bf16(const float* __restrict__ src,
                                                  unsigned short* __restrict__ hi,
                                                  unsigned short* __restrict__ lo, int n4)
{
    int i = blockIdx.x * blockDim.x + threadIdx.x;
    if (i >= n4) return;
    float4 v = *(const float4*)(src + (size_t)i * 4);
    ushort4 h, l;
    h.x = f2bf(v.x); l.x = f2bf(v.x - bf2f(h.x));
    h.y = f2bf(v.y); l.y = f2bf(v.y - bf2f(h.y));
    h.z = f2bf(v.z); l.z = f2bf(v.z - bf2f(h.z));
    h.w = f2bf(v.w); l.w = f2bf(v.w - bf2f(h.w));
    *(ushort4*)(hi + (size_t)i * 4) = h;
    *(ushort4*)(lo + (size_t)i * 4) = l;
}

// ---------------------------------------------------------------------------
// bf16x3 split-accumulation MFMA GEMM:
//   C[M,Nc] (+)= A[M,K] @ B^T   where B stored row-major [Nc][K]  (LSTM weights)
// A,B given as bf16 hi/lo pairs; product = ah*bh + ah*bl + al*bh (fp32 acc).
// Tile 128x128, BK=32, 256 thr = 4 waves (2x2), wave = 64x64 = 4x4 frags of
// v_mfma_f32_16x16x32_bf16. C/D layout per m89: col=lane&15, row=(lane>>4)*4+v.
// A-frag: lane holds A[row=lane&15][8g..8g+8), g=lane>>4 ; B-frag same on [n][k].
// LDS [128][32] bf16 tiles with 16B-slot swizzle: slot ^= (row>>1)&3
//   -> conflict-free ds_read_b128 frag loads; staging writes row-contiguous.
// Requires Nc%128==0, K%32==0; M guarded (OOB rows clamp-load garbage, no write).
// ---------------------------------------------------------------------------
template<bool ACC>
__global__ __launch_bounds__(256) void gemm_bt_mfma3(
    const unsigned short* __restrict__ Ahi, const unsigned short* __restrict__ Alo,
    const unsigned short* __restrict__ Bhi, const unsigned short* __restrict__ Blo,
    float* __restrict__ C, int M, int Nc, int K)
{
    __shared__ __align__(16) unsigned short sAh[128*32];
    __shared__ __align__(16) unsigned short sAl[128*32];
    __shared__ __align__(16) unsigned short sBh[128*32];
    __shared__ __align__(16) unsigned short sBl[128*32];

    const int tid  = threadIdx.x;
    const int lane = tid & 63;
    const int wave = tid >> 6;
    const int wr = wave >> 1, wc = wave & 1;
    const int brow = blockIdx.y * 128, bcol = blockIdx.x * 128;

    f4v acc[4][4];
#pragma unroll
    for (int i = 0; i < 4; ++i)
#pragma unroll
        for (int j = 0; j < 4; ++j) acc[i][j] = (f4v){0.f, 0.f, 0.f, 0.f};

    // staging: thread handles rows sr, sr+64; 16B chunk sc (8 bf16)
    const int sr = tid >> 2;
    const int sc = tid & 3;
    const int swz = (sc ^ ((sr >> 1) & 3)) * 8;       // (sr+64)>>1 has same &3
    const int wo0 = sr * 32 + swz;
    const int wo1 = wo0 + 64 * 32;

    int ar0 = brow + sr;      if (ar0 >= M) ar0 = 0;  // clamp: garbage row, never stored
    int ar1 = brow + sr + 64; if (ar1 >= M) ar1 = 0;
    const size_t aoff0 = (size_t)ar0 * K + sc * 8;
    const size_t aoff1 = (size_t)ar1 * K + sc * 8;
    const size_t boff0 = (size_t)(bcol + sr) * K + sc * 8;
    const size_t boff1 = (size_t)(bcol + sr + 64) * K + sc * 8;

    const int g  = lane >> 4;
    const int fr = lane & 15;

    // prefetch kt=0
    s8v vAh0 = *(const s8v*)(Ahi + aoff0), vAh1 = *(const s8v*)(Ahi + aoff1);
    s8v vAl0 = *(const s8v*)(Alo + aoff0), vAl1 = *(const s8v*)(Alo + aoff1);
    s8v vBh0 = *(const s8v*)(Bhi + boff0), vBh1 = *(const s8v*)(Bhi + boff1);
    s8v vBl0 = *(const s8v*)(Blo + boff0), vBl1 = *(const s8v*)(Blo + boff1);

    for (int kt = 0; kt < K; kt += 32) {
        __syncthreads();   // previous iter's frag reads done
        *(s8v*)(sAh + wo0) = vAh0;  *(s8v*)(sAh + wo1) = vAh1;
        *(s8v*)(sAl + wo0) = vAl0;  *(s8v*)(sAl + wo1) = vAl1;
        *(s8v*)(sBh + wo0) = vBh0;  *(s8v*)(sBh + wo1) = vBh1;
        *(s8v*)(sBl + wo0) = vBl0;  *(s8v*)(sBl + wo1) = vBl1;
        __syncthreads();

        if (kt + 32 < K) {   // reg-prefetch next k-slab; latency hides under MFMA
            int kn = kt + 32;
            vAh0 = *(const s8v*)(Ahi + aoff0 + kn); vAh1 = *(const s8v*)(Ahi + aoff1 + kn);
            vAl0 = *(const s8v*)(Alo + aoff0 + kn); vAl1 = *(const s8v*)(Alo + aoff1 + kn);
            vBh0 = *(const s8v*)(Bhi + boff0 + kn); vBh1 = *(const s8v*)(Bhi + boff1 + kn);
            vBl0 = *(const s8v*)(Blo + boff0 + kn); vBl1 = *(const s8v*)(Blo + boff1 + kn);
        }

        s8v ah[4], al[4], bh[4], bl[4];
#pragma unroll
        for (int mi = 0; mi < 4; ++mi) {
            int row = wr * 64 + mi * 16 + fr;
            int off = row * 32 + ((g ^ ((row >> 1) & 3)) * 8);
            ah[mi] = *(const s8v*)(sAh + off);
            al[mi] = *(const s8v*)(sAl + off);
        }
#pragma unroll
        for (int ni = 0; ni < 4; ++ni) {
            int row = wc * 64 + ni * 16 + fr;
            int off = row * 32 + ((g ^ ((row >> 1) & 3)) * 8);
            bh[ni] = *(const s8v*)(sBh + off);
            bl[ni] = *(const s8v*)(sBl + off);
        }
#pragma unroll
        for (int mi = 0; mi < 4; ++mi)
#pragma unroll
            for (int ni = 0; ni < 4; ++ni) {
                acc[mi][ni] = __builtin_amdgcn_mfma_f32_16x16x32_bf16(ah[mi], bh[ni], acc[mi][ni], 0, 0, 0);
                acc[mi][ni] = __builtin_amdgcn_mfma_f32_16x16x32_bf16(ah[mi], bl[ni], acc[mi][ni], 0, 0, 0);
                acc[mi][ni] = __builtin_amdgcn_mfma_f32_16x16x32_bf16(al[mi], bh[ni], acc[mi][ni], 0, 0, 0);
            }
    }

#pragma unroll
    for (int mi = 0; mi < 4; ++mi) {
#pragma unroll
        for (int v = 0; v < 4; ++v) {
            int row = brow + wr * 64 + mi * 16 + g * 4 + v;
            if (row >= M) continue;
            float* cp = C + (size_t)row * Nc + bcol + wc * 64 + fr;
#pragma unroll
            for (int ni = 0; ni < 4; ++ni) {
                float val = acc[mi][ni][v];
                if (ACC) val += cp[ni * 16];
                cp[ni * 16] = val;
            }
        }
    }
}

// ---------------------------------------------------------------------------
// Tiled fp32 GEMM (GAT projections only): C[M,Nc] = A[M,K] @ B[K,Nc]
// ---------------------------------------------------------------------------
template<bool BT, bool ACC>
__global__ __launch_bounds__(256) void gemm128(const float* __restrict__ A,
                                               const float* __restrict__ B,
                                               float* __restrict__ C,
                                               int M, int Nc, int K)
{
    __shared__ float As[16][128];
    __shared__ float Bs[16][128];
    const int tid = threadIdx.x;
    const int tx = tid & 15, ty = tid >> 4;
    const int brow = blockIdx.y * 128, bcol = blockIdx.x * 128;

    float acc[8][8];
#pragma unroll
    for (int i = 0; i < 8; ++i)
#pragma unroll
        for (int j = 0; j < 8; ++j) acc[i][j] = 0.f;

    const int lr = tid >> 1;
    const int lk = (tid & 1) * 8;
    const int bkr = tid >> 4;
    const int bcc = (tid & 15) * 8;

    for (int kt = 0; kt < K; kt += 16) {
        {
            int gr = brow + lr;
            float4 v0 = make_float4(0.f,0.f,0.f,0.f), v1 = v0;
            if (gr < M) {
                const float* p = A + (size_t)gr * K + kt + lk;
                v0 = *(const float4*)p; v1 = *(const float4*)(p + 4);
            }
            As[lk+0][lr] = v0.x; As[lk+1][lr] = v0.y; As[lk+2][lr] = v0.z; As[lk+3][lr] = v0.w;
            As[lk+4][lr] = v1.x; As[lk+5][lr] = v1.y; As[lk+6][lr] = v1.z; As[lk+7][lr] = v1.w;
        }
        if (BT) {
            int gj = bcol + lr;
            const float* p = B + (size_t)gj * K + kt + lk;
            float4 v0 = *(const float4*)p, v1 = *(const float4*)(p + 4);
            Bs[lk+0][lr] = v0.x; Bs[lk+1][lr] = v0.y; Bs[lk+2][lr] = v0.z; Bs[lk+3][lr] = v0.w;
            Bs[lk+4][lr] = v1.x; Bs[lk+5][lr] = v1.y; Bs[lk+6][lr] = v1.z; Bs[lk+7][lr] = v1.w;
        } else {
            const float* p = B + (size_t)(kt + bkr) * Nc + bcol + bcc;
            *(float4*)&Bs[bkr][bcc]     = *(const float4*)p;
            *(float4*)&Bs[bkr][bcc + 4] = *(const float4*)(p + 4);
        }
        __syncthreads();
#pragma unroll
        for (int k = 0; k < 16; ++k) {
            float a[8], b[8];
            *(float4*)&a[0] = *(const float4*)&As[k][ty * 4];
            *(float4*)&a[4] = *(const float4*)&As[k][64 + ty * 4];
            *(float4*)&b[0] = *(const float4*)&Bs[k][tx * 4];
            *(float4*)&b[4] = *(const float4*)&Bs[k][64 + tx * 4];
#pragma unroll
            for (int i = 0; i < 8; ++i)
#pragma unroll
                for (int j = 0; j < 8; ++j) acc[i][j] = fmaf(a[i], b[j], acc[i][j]);
        }
        __syncthreads();
    }
#pragma unroll
    for (int i = 0; i < 8; ++i) {
        int r = brow + ((i < 4) ? (ty * 4 + i) : (64 + ty * 4 + i - 4));
        if (r >= M) continue;
#pragma unroll
        for (int jh = 0; jh < 2; ++jh) {
            int cc = bcol + jh * 64 + tx * 4;
            float* cp = C + (size_t)r * Nc + cc;
            float4 v = make_float4(acc[i][jh*4+0], acc[i][jh*4+1], acc[i][jh*4+2], acc[i][jh*4+3]);
            if (ACC) { float4 o = *(const float4*)cp; v.x += o.x; v.y += o.y; v.z += o.z; v.w += o.w; }
            *(float4*)cp = v;
        }
    }
}

// ---------------------------------------------------------------------------
// CSR build (dest-sorted incoming-edge lists, self loop first in each segment)
// ---------------------------------------------------------------------------
__global__ void deg_init(int* deg, int n) {
    int i = blockIdx.x * blockDim.x + threadIdx.x;
    if (i < n) deg[i] = 1;
}
__global__ void hist_dest(const int* __restrict__ dst, int* deg, int e) {
    for (int i = blockIdx.x * blockDim.x + threadIdx.x; i < e; i += gridDim.x * blockDim.x)
        atomicAdd(&deg[dst[i]], 1);
}
__global__ void scan_excl(const int* __restrict__ deg, int* __restrict__ off, int n) {
    __shared__ int s[1024];
    __shared__ int carry;
    int tid = threadIdx.x;
    if (tid == 0) { carry = 0; off[0] = 0; }
    __syncthreads();
    for (int base = 0; base < n; base += 1024) {
        int i = base + tid;
        s[tid] = (i < n) ? deg[i] : 0;
        __syncthreads();
        for (int st = 1; st < 1024; st <<= 1) {
            int t = (tid >= st) ? s[tid - st] : 0;
            __syncthreads();
            s[tid] += t;
            __syncthreads();
        }
        int incl = s[tid] + carry;
        if (i < n) off[i + 1] = incl;
        __syncthreads();
        if (tid == 1023) carry = incl;
        __syncthreads();
    }
}
__global__ void scatter_self(const int* __restrict__ off, int* cur, int* srcI, int n) {
    int i = blockIdx.x * blockDim.x + threadIdx.x;
    if (i < n) { int p = off[i]; srcI[p] = i; cur[i] = p + 1; }
}
__global__ void scatter_edges(const int* __restrict__ es, const int* __restrict__ ed,
                              int* cur, int* srcI, int e) {
    for (int i = blockIdx.x * blockDim.x + threadIdx.x; i < e; i += gridDim.x * blockDim.x) {
        int p = atomicAdd(&cur[ed[i]], 1);
        srcI[p] = es[i];
    }
}

// ---------------------------------------------------------------------------
// GAT attention coefficients; one wave per node.
// ---------------------------------------------------------------------------
__global__ __launch_bounds__(256) void attn_ab(const float* __restrict__ h,
                                               const float* __restrict__ asrc,
                                               const float* __restrict__ adst,
                                               float* __restrict__ a_s, float* __restrict__ a_d, int n)
{
    int node = blockIdx.x * 4 + (threadIdx.x >> 6);
    if (node >= n) return;
    int lane = threadIdx.x & 63;
    const float* hp = h + (size_t)node * CDIM + lane * 8;
    float4 h0 = *(const float4*)hp, h1 = *(const float4*)(hp + 4);
    float4 w0 = *(const float4*)(asrc + lane * 8);
    float4 w1 = *(const float4*)(asrc + lane * 8 + 4);
    float4 u0 = *(const float4*)(adst + lane * 8);
    float4 u1 = *(const float4*)(adst + lane * 8 + 4);
    float s = h0.x*w0.x + h0.y*w0.y + h0.z*w0.z + h0.w*w0.w
            + h1.x*w1.x + h1.y*w1.y + h1.z*w1.z + h1.w*w1.w;
    float d = h0.x*u0.x + h0.y*u0.y + h0.z*u0.z + h0.w*u0.w
            + h1.x*u1.x + h1.y*u1.y + h1.z*u1.z + h1.w*u1.w;
#pragma unroll
    for (int m = 8; m >= 1; m >>= 1) { s += __shfl_xor(s, m); d += __shfl_xor(d, m); }
    if ((lane & 15) == 0) {
        int head = lane >> 4;
        a_s[node * 4 + head] = s;
        a_d[node * 4 + head] = d;
    }
}

// ---------------------------------------------------------------------------
// GAT aggregate: one wave per dest node; 3 passes (max, exp-sum, gather).
// ---------------------------------------------------------------------------
__global__ __launch_bounds__(256) void gat_agg(const float* __restrict__ h,
                                               const float* __restrict__ a_s,
                                               const float* __restrict__ a_d,
                                               const int* __restrict__ off,
                                               const int* __restrict__ srcI,
                                               const float* __restrict__ bias,
                                               float* __restrict__ out, int n)
{
    int node = blockIdx.x * 4 + (threadIdx.x >> 6);
    if (node >= n) return;
    int lane = threadIdx.x & 63;
    int o0 = off[node], o1 = off[node + 1];
    float4 ad4 = *(const float4*)(a_d + node * 4);
    float ad[4] = {ad4.x, ad4.y, ad4.z, ad4.w};

    float mx[4] = {-3.4e38f, -3.4e38f, -3.4e38f, -3.4e38f};
    for (int e = o0 + lane; e < o1; e += 64) {
        int s = srcI[e];
        float4 as4 = *(const float4*)(a_s + s * 4);
        float as[4] = {as4.x, as4.y, as4.z, as4.w};
#pragma unroll
        for (int hh = 0; hh < 4; ++hh) mx[hh] = fmaxf(mx[hh], lrelu(as[hh] + ad[hh]));
    }
#pragma unroll
    for (int m = 32; m >= 1; m >>= 1)
#pragma unroll
        for (int hh = 0; hh < 4; ++hh) mx[hh] = fmaxf(mx[hh], __shfl_xor(mx[hh], m));

    float den[4] = {0.f, 0.f, 0.f, 0.f};
    for (int e = o0 + lane; e < o1; e += 64) {
        int s = srcI[e];
        float4 as4 = *(const float4*)(a_s + s * 4);
        float as[4] = {as4.x, as4.y, as4.z, as4.w};
#pragma unroll
        for (int hh = 0; hh < 4; ++hh) den[hh] += expf(lrelu(as[hh] + ad[hh]) - mx[hh]);
    }
#pragma unroll
    for (int m = 32; m >= 1; m >>= 1)
#pragma unroll
        for (int hh = 0; hh < 4; ++hh) den[hh] += __shfl_xor(den[hh], m);

    int myh = lane >> 4;
    float admy = ad[myh], mmy = mx[myh], dinv = 1.f / den[myh];
    float acc[8] = {0.f,0.f,0.f,0.f,0.f,0.f,0.f,0.f};
    int e = o0;
    for (; e + 1 < o1; e += 2) {
        int s0 = srcI[e], s1 = srcI[e + 1];
        float al0 = expf(lrelu(a_s[s0 * 4 + myh] + admy) - mmy) * dinv;
        float al1 = expf(lrelu(a_s[s1 * 4 + myh] + admy) - mmy) * dinv;
        const float* hp0 = h + (size_t)s0 * CDIM + lane * 8;
        const float* hp1 = h + (size_t)s1 * CDIM + lane * 8;
        float4 a0 = *(const float4*)hp0, a1 = *(const float4*)(hp0 + 4);
        float4 b0 = *(const float4*)hp1, b1 = *(const float4*)(hp1 + 4);
        acc[0] = fmaf(al0, a0.x, acc[0]); acc[1] = fmaf(al0, a0.y, acc[1]);
        acc[2] = fmaf(al0, a0.z, acc[2]); acc[3] = fmaf(al0, a0.w, acc[3]);
        acc[4] = fmaf(al0, a1.x, acc[4]); acc[5] = fmaf(al0, a1.y, acc[5]);
        acc[6] = fmaf(al0, a1.z, acc[6]); acc[7] = fmaf(al0, a1.w, acc[7]);
        acc[0] = fmaf(al1, b0.x, acc[0]); acc[1] = fmaf(al1, b0.y, acc[1]);
        acc[2] = fmaf(al1, b0.z, acc[2]); acc[3] = fmaf(al1, b0.w, acc[3]);
        acc[4] = fmaf(al1, b1.x, acc[4]); acc[5] = fmaf(al1, b1.y, acc[5]);
        acc[6] = fmaf(al1, b1.z, acc[6]); acc[7] = fmaf(al1, b1.w, acc[7]);
    }
    for (; e < o1; ++e) {
        int s = srcI[e];
        float alpha = expf(lrelu(a_s[s * 4 + myh] + admy) - mmy) * dinv;
        const float* hp = h + (size_t)s * CDIM + lane * 8;
        float4 h0 = *(const float4*)hp, h1 = *(const float4*)(hp + 4);
        acc[0] = fmaf(alpha, h0.x, acc[0]); acc[1] = fmaf(alpha, h0.y, acc[1]);
        acc[2] = fmaf(alpha, h0.z, acc[2]); acc[3] = fmaf(alpha, h0.w, acc[3]);
        acc[4] = fmaf(alpha, h1.x, acc[4]); acc[5] = fmaf(alpha, h1.y, acc[5]);
        acc[6] = fmaf(alpha, h1.z, acc[6]); acc[7] = fmaf(alpha, h1.w, acc[7]);
    }
    const float* bp = bias + lane * 8;
    float4 b0 = *(const float4*)bp, b1 = *(const float4*)(bp + 4);
    float* op = out + (size_t)node * CDIM + lane * 8;
    float4 r0, r1;
    r0.x = fmaxf(acc[0] + b0.x, 0.f); r0.y = fmaxf(acc[1] + b0.y, 0.f);
    r0.z = fmaxf(acc[2] + b0.z, 0.f); r0.w = fmaxf(acc[3] + b0.w, 0.f);
    r1.x = fmaxf(acc[4] + b1.x, 0.f); r1.y = fmaxf(acc[5] + b1.y, 0.f);
    r1.z = fmaxf(acc[6] + b1.z, 0.f); r1.w = fmaxf(acc[7] + b1.w, 0.f);
    *(float4*)op = r0; *(float4*)(op + 4) = r1;
}

// ---------------------------------------------------------------------------
// LSTM pointwise: gates(+biases) -> c update; h emitted directly as bf16 hi/lo
// (next step's recurrent GEMM operand). Fused JK score dot.
// ---------------------------------------------------------------------------
__global__ __launch_bounds__(256) void lstm_pw2(const float* __restrict__ gates,
                                                const float* __restrict__ bih,
                                                const float* __restrict__ bhh,
                                                unsigned short* __restrict__ hhi,
                                                unsigned short* __restrict__ hlo,
                                                float* __restrict__ c,
                                                const float* __restrict__ attw,
                                                float* __restrict__ scoreOut, int first)
{
    int r = blockIdx.x, tid = threadIdx.x;
    const float* gr = gates + (size_t)r * GATE;
    float part = 0.f;
#pragma unroll
    for (int q = 0; q < 3; ++q) {
        int j = tid + q * 256;
        float gi = gr[j]        + bih[j]        + bhh[j];
        float gf = gr[768 + j]  + bih[768 + j]  + bhh[768 + j];
        float gg = gr[1536 + j] + bih[1536 + j] + bhh[1536 + j];
        float go = gr[2304 + j] + bih[2304 + j] + bhh[2304 + j];
        float cold = first ? 0.f : c[(size_t)r * HLDIM + j];
        float cn = sigf(gf) * cold + sigf(gi) * tanhf(gg);
        float hn = sigf(go) * tanhf(cn);
        c[(size_t)r * HLDIM + j] = cn;
        unsigned short hb = f2bf(hn);
        hhi[(size_t)r * HLDIM + j] = hb;
        hlo[(size_t)r * HLDIM + j] = f2bf(hn - bf2f(hb));
        part = fmaf(hn, attw[j], part);
    }
    __shared__ float red[256];
    red[tid] = part;
    __syncthreads();
    for (int s = 128; s > 0; s >>= 1) { if (tid < s) red[tid] += red[tid + s]; __syncthreads(); }
    if (tid == 0) scoreOut[r] = red[0];
}

// ---------------------------------------------------------------------------
// Final: JK softmax over layers, per-graph mean pool, fc1-relu, fc2-relu, fc3.
// ---------------------------------------------------------------------------
__device__ __forceinline__ int lower_bound_i(const int* a, int n, int v) {
    int lo = 0, hi = n;
    while (lo < hi) { int m = (lo + hi) >> 1; if (a[m] < v) lo = m + 1; else hi = m; }
    return lo;
}

__global__ __launch_bounds__(256) void final_pool_mlp(
    const float* __restrict__ X0, const float* __restrict__ X1, const float* __restrict__ X2,
    const float* __restrict__ scF, const float* __restrict__ scR, const float* __restrict__ attbp,
    const int* __restrict__ batch,
    const float* __restrict__ fc1W, const float* __restrict__ fc1b,
    const float* __restrict__ fc2W, const float* __restrict__ fc2b,
    const float* __restrict__ fc3W, const float* __restrict__ fc3b,
    float* __restrict__ out, int n)
{
    __shared__ float bufA[512];
    __shared__ float bufB[512];
    int g = blockIdx.x, tid = threadIdx.x;
    int lo = lower_bound_i(batch, n, g), hi = lower_bound_i(batch, n, g + 1);
    float attb = *attbp;
    float acc0 = 0.f, acc1 = 0.f;
    for (int nd = lo; nd < hi; ++nd) {
        float s0 = scF[nd]         + scR[nd]         + attb;
        float s1 = scF[n + nd]     + scR[n + nd]     + attb;
        float s2 = scF[2 * n + nd] + scR[2 * n + nd] + attb;
        float m = fmaxf(s0, fmaxf(s1, s2));
        float e0 = expf(s0 - m), e1 = expf(s1 - m), e2 = expf(s2 - m);
        float inv = 1.f / (e0 + e1 + e2);
        float a0 = e0 * inv, a1 = e1 * inv, a2 = e2 * inv;
        size_t b = (size_t)nd * CDIM;
        acc0 += a0 * X0[b + tid]       + a1 * X1[b + tid]       + a2 * X2[b + tid];
        acc1 += a0 * X0[b + 256 + tid] + a1 * X1[b + 256 + tid] + a2 * X2[b + 256 + tid];
    }
    float cinv = 1.f / (float)((hi - lo) > 0 ? (hi - lo) : 1);
    bufA[tid] = acc0 * cinv; bufA[tid + 256] = acc1 * cinv;
    __syncthreads();
    float v0 = 0.f, v1 = 0.f;
#pragma unroll 8
    for (int k = 0; k < 512; ++k) {
        float gk = bufA[k];
        v0 = fmaf(gk, fc1W[k * 512 + tid], v0);
        v1 = fmaf(gk, fc1W[k * 512 + 256 + tid], v1);
    }
    bufB[tid] = fmaxf(v0 + fc1b[tid], 0.f);
    bufB[tid + 256] = fmaxf(v1 + fc1b[tid + 256], 0.f);
    __syncthreads();
    v0 = 0.f; v1 = 0.f;
#pragma unroll 8
    for (int k = 0; k < 512; ++k) {
        float hk = bufB[k];
        v0 = fmaf(hk, fc2W[k * 512 + tid], v0);
        v1 = fmaf(hk, fc2W[k * 512 + 256 + tid], v1);
    }
    bufA[tid] = fmaxf(v0 + fc2b[tid], 0.f);
    bufA[tid + 256] = fmaxf(v1 + fc2b[tid + 256], 0.f);
    __syncthreads();
    int j = tid & 7, k0 = tid >> 3;
    float p = 0.f;
    for (int k = k0; k < 512; k += 32) p = fmaf(bufA[k], fc3W[k * 8 + j], p);
    bufB[tid] = p;
    __syncthreads();
    if (tid < 8) {
        float s = 0.f;
        for (int m = 0; m < 32; ++m) s += bufB[tid + 8 * m];
        out[g * 8 + tid] = s + fc3b[tid];
    }
}

// ---------------------------------------------------------------------------
extern "C" void kernel_launch(void* const* d_in, const int* in_sizes, int n_in,
                              void* d_out, int out_size, void* d_ws, size_t ws_size,
                              hipStream_t stream)
{
    (void)in_sizes; (void)n_in; (void)out_size;
    const float* x     = (const float*)d_in[0];
    const int*   eidx  = (const int*)d_in[1];     // (2,E): row0 = src, row1 = dst
    const int*   batch = (const int*)d_in[2];
    const float* W[3]    = {(const float*)d_in[3],  (const float*)d_in[7],  (const float*)d_in[11]};
    const float* asrc[3] = {(const float*)d_in[4],  (const float*)d_in[8],  (const float*)d_in[12]};
    const float* adst[3] = {(const float*)d_in[5],  (const float*)d_in[9],  (const float*)d_in[13]};
    const float* bgat[3] = {(const float*)d_in[6],  (const float*)d_in[10], (const float*)d_in[14]};
    const float* Wih[2]  = {(const float*)d_in[15], (const float*)d_in[19]};
    const float* Whh[2]  = {(const float*)d_in[16], (const float*)d_in[20]};
    const float* bih[2]  = {(const float*)d_in[17], (const float*)d_in[21]};
    const float* bhh[2]  = {(const float*)d_in[18], (const float*)d_in[22]};
    const float* attw = (const float*)d_in[23];
    const float* attb = (const float*)d_in[24];
    const float* fc1W = (const float*)d_in[25];
    const float* fc1b = (const float*)d_in[26];
    const float* fc2W = (const float*)d_in[27];
    const float* fc2b = (const float*)d_in[28];
    const float* fc3W = (const float*)d_in[29];
    const float* fc3b = (const float*)d_in[30];
    float* out = (float*)d_out;

    // ---- workspace layout (byte allocator, 64B aligned) ----
    char* base = (char*)d_ws;
    size_t off = 0;
    auto alloc = [&](size_t bytes) -> void* {
        off = (off + 63) & ~(size_t)63;
        void* p = base + off; off += bytes; return p;
    };
    float* Xall = (float*)alloc((size_t)3 * N_NODES * CDIM * 4);   // X0|X1|X2 contiguous
    float* X0 = Xall, *X1 = Xall + (size_t)N_NODES * CDIM, *X2 = X1 + (size_t)N_NODES * CDIM;
    float* cbuf = (float*)alloc((size_t)N_NODES * HLDIM * 4);
    float* a_s  = (float*)alloc((size_t)N_NODES * 4 * 4);
    float* a_d  = (float*)alloc((size_t)N_NODES * 4 * 4);
    float* scF  = (float*)alloc((size_t)3 * N_NODES * 4);
    float* scR  = (float*)alloc((size_t)3 * N_NODES * 4);
    unsigned short* Xhi = (unsigned short*)alloc((size_t)3 * N_NODES * CDIM * 2);
    unsigned short* Xlo = (unsigned short*)alloc((size_t)3 * N_NODES * CDIM * 2);
    unsigned short* hhi = (unsigned short*)alloc((size_t)N_NODES * HLDIM * 2);
    unsigned short* hlo = (unsigned short*)alloc((size_t)N_NODES * HLDIM * 2);
    unsigned short* wihH[2], *wihL[2], *whhH[2], *whhL[2];
    for (int d = 0; d < 2; ++d) {
        wihH[d] = (unsigned short*)alloc((size_t)GATE * CDIM * 2);
        wihL[d] = (unsigned short*)alloc((size_t)GATE * CDIM * 2);
        whhH[d] = (unsigned short*)alloc((size_t)GATE * HLDIM * 2);
        whhL[d] = (unsigned short*)alloc((size_t)GATE * HLDIM * 2);
    }
    int* offI = (int*)alloc((size_t)(N_NODES + 1) * 4);
    int* srcI = (int*)alloc((size_t)(N_EDGES + N_NODES) * 4);
    int* degI = (int*)alloc((size_t)N_NODES * 4);
    off = (off + 63) & ~(size_t)63;
    float* tail = (float*)(base + off);              // time-shared: hproj | gates
    size_t tailF = (ws_size > off) ? (ws_size - off) / 4 : 0;
    float* hproj = tail;
    float* gates = tail;
    int chunkRows = (int)(tailF / GATE);
    if (chunkRows > N_NODES) chunkRows = N_NODES;
    if (chunkRows < 128) chunkRows = 128;            // assumes ws >= ~260 MB

    // ---- CSR by destination (self loop first per segment) ----
    deg_init<<<(N_NODES + 255) / 256, 256, 0, stream>>>(degI, N_NODES);
    hist_dest<<<512, 256, 0, stream>>>(eidx + N_EDGES, degI, N_EDGES);
    scan_excl<<<1, 1024, 0, stream>>>(degI, offI, N_NODES);
    scatter_self<<<(N_NODES + 255) / 256, 256, 0, stream>>>(offI, degI, srcI, N_NODES);
    scatter_edges<<<512, 256, 0, stream>>>(eidx, eidx + N_EDGES, degI, srcI, N_EDGES);

    // ---- LSTM weight hi/lo splits (independent of GAT) ----
    for (int d = 0; d < 2; ++d) {
        int n4i = GATE * CDIM / 4, n4h = GATE * HLDIM / 4;
        split_bf16<<<(n4i + 255) / 256, 256, 0, stream>>>(Wih[d], wihH[d], wihL[d], n4i);
        split_bf16<<<(n4h + 255) / 256, 256, 0, stream>>>(Whh[d], whhH[d], whhL[d], n4h);
    }

    // ---- GAT layers (fp32) ----
    float* Xl[3] = {X0, X1, X2};
    const float* cur_in = x;
    int Kd = 128;
    for (int l = 0; l < 3; ++l) {
        dim3 gg(CDIM / 128, (N_NODES + 127) / 128);
        gemm128<false, false><<<gg, 256, 0, stream>>>(cur_in, W[l], hproj, N_NODES, CDIM, Kd);
        attn_ab<<<(N_NODES + 3) / 4, 256, 0, stream>>>(hproj, asrc[l], adst[l], a_s, a_d, N_NODES);
        gat_agg<<<(N_NODES + 3) / 4, 256, 0, stream>>>(hproj, a_s, a_d, offI, srcI, bgat[l], Xl[l], N_NODES);
        cur_in = Xl[l];
        Kd = CDIM;
    }

    // ---- X hi/lo split (stacked [3N][CDIM], contiguous) ----
    {
        int n4 = 3 * N_NODES * CDIM / 4;
        split_bf16<<<(n4 + 255) / 256, 256, 0, stream>>>(Xall, Xhi, Xlo, n4);
    }

    // ---- Bidirectional LSTM (seq len 3), bf16x3 MFMA GEMMs ----
    for (int dir = 0; dir < 2; ++dir) {
        const float* aw = attw + dir * HLDIM;
        float* sc = (dir == 0) ? scF : scR;
        for (int cs = 0; cs < N_NODES; cs += chunkRows) {
            int rows = (N_NODES - cs < chunkRows) ? (N_NODES - cs) : chunkRows;
            dim3 gg(GATE / 128, (rows + 127) / 128);
            for (int t = 0; t < 3; ++t) {
                int l = (dir == 0) ? t : (2 - t);
                size_t xo = ((size_t)l * N_NODES + cs) * CDIM;
                gemm_bt_mfma3<false><<<gg, 256, 0, stream>>>(
                    Xhi + xo, Xlo + xo, wihH[dir], wihL[dir], gates, rows, GATE, CDIM);
                if (t > 0)
                    gemm_bt_mfma3<true><<<gg, 256, 0, stream>>>(
                        hhi + (size_t)cs * HLDIM, hlo + (size_t)cs * HLDIM,
                        whhH[dir], whhL[dir], gates, rows, GATE, HLDIM);
                lstm_pw2<<<rows, 256, 0, stream>>>(gates, bih[dir], bhh[dir],
                                                   hhi + (size_t)cs * HLDIM,
                                                   hlo + (size_t)cs * HLDIM,
                                                   cbuf + (size_t)cs * HLDIM,
                                                   aw, sc + (size_t)l * N_NODES + cs, t == 0 ? 1 : 0);
            }
        }
    }

    // ---- JK attention + mean pool + MLP head ----
    final_pool_mlp<<<NGRAPH, 256, 0, stream>>>(X0, X1, X2, scF, scR, attb, batch,
                                               fc1W, fc1b, fc2W, fc2b, fc3W, fc3b,
                                               out, N_NODES);
}

// Round 7
// 1720.380 us; speedup vs baseline: 1.4596x; 1.4596x over previous
//
#include <hip/hip_runtime.h>
#include <math.h>

#define N_NODES 10000
#define N_EDGES 160000
#define NGRAPH  64
#define CDIM    512        // HEADS*HID
#define HEADS   4
#define HLDIM   768
#define GATE    (4*HLDIM)  // 3072
#define NEG     0.2f

typedef __attribute__((ext_vector_type(8))) short s8v;   // 8 bf16 = 4 VGPR (MFMA A/B frag)
typedef __attribute__((ext_vector_type(4))) float f4v;   // MFMA C/D frag

__device__ __forceinline__ float lrelu(float x){ return x > 0.f ? x : NEG * x; }
__device__ __forceinline__ float sigf (float x){ return 1.f / (1.f + expf(-x)); }

// RNE float->bf16 (finite data only) and exact bf16->float
__device__ __forceinline__ unsigned short f2bf(float f) {
    unsigned u = __float_as_uint(f);
    u += 0x7fffu + ((u >> 16) & 1u);
    return (unsigned short)(u >> 16);
}
__device__ __forceinline__ float bf2f(unsigned short h) {
    return __uint_as_float(((unsigned)h) << 16);
}

// ---------------------------------------------------------------------------
// split fp32 -> (bf16 hi, bf16 lo): x ~= hi + lo, err ~ 2^-16 relative
// ---------------------------------------------------------------------------
__global__ __launch_bounds__(256) void split_bf16(const float* __restrict__ src,
                                                  unsigned short* __restrict__ hi,
                                                  unsigned short* __restrict__ lo, int n4)
{
    int i = blockIdx.x * blockDim.x + threadIdx.x;
    if (i >= n4) return;
    float4 v = *(const float4*)(src + (size_t)i * 4);
    ushort4 h, l;
    h.x = f2bf(v.x); l.x = f2bf(v.x - bf2f(h.x));
    h.y = f2bf(v.y); l.y = f2bf(v.y - bf2f(h.y));
    h.z = f2bf(v.z); l.z = f2bf(v.z - bf2f(h.z));
    h.w = f2bf(v.w); l.w = f2bf(v.w - bf2f(h.w));
    *(ushort4*)(hi + (size_t)i * 4) = h;
    *(ushort4*)(lo + (size_t)i * 4) = l;
}

// plain fp32 -> bf16 cast (LSTM weights / activations, single precision path)
__global__ __launch_bounds__(256) void cast_bf16(const float* __restrict__ src,
                                                 unsigned short* __restrict__ dst, int n4)
{
    int i = blockIdx.x * blockDim.x + threadIdx.x;
    if (i >= n4) return;
    float4 v = *(const float4*)(src + (size_t)i * 4);
    ushort4 h;
    h.x = f2bf(v.x); h.y = f2bf(v.y); h.z = f2bf(v.z); h.w = f2bf(v.w);
    *(ushort4*)(dst + (size_t)i * 4) = h;
}

// ---------------------------------------------------------------------------
// W [K][Nc] fp32 -> WT [Nc][K] bf16 hi/lo  (GAT weights; K,Nc multiples of 32)
// ---------------------------------------------------------------------------
__global__ void transp_split(const float* __restrict__ W,
                             unsigned short* __restrict__ hi,
                             unsigned short* __restrict__ lo, int K, int Nc)
{
    __shared__ float t[32][33];
    int bx = blockIdx.x * 32, by = blockIdx.y * 32;   // bx: Nc tile, by: K tile
    int tx = threadIdx.x, ty = threadIdx.y;           // 32 x 8
    for (int r = 0; r < 32; r += 8)
        t[ty + r][tx] = W[(size_t)(by + ty + r) * Nc + bx + tx];
    __syncthreads();
    for (int r = 0; r < 32; r += 8) {
        int n = bx + ty + r, k = by + tx;
        float v = t[tx][ty + r];
        unsigned short h = f2bf(v);
        hi[(size_t)n * K + k] = h;
        lo[(size_t)n * K + k] = f2bf(v - bf2f(h));
    }
}

// ---------------------------------------------------------------------------
// bf16x3 split-accumulation MFMA GEMM (GAT projections — fp32-grade accuracy):
//   C[M,Nc] (+)= A[M,K] @ B^T, B stored [Nc][K]; product ah*bh+ah*bl+al*bh.
// Tile 128x128, BK=32, 4 waves (2x2), 4x4 frags of v_mfma_f32_16x16x32_bf16.
// C/D map (m89): col=lane&15, row=(lane>>4)*4+v. LDS 16B-slot swizzle.
// ---------------------------------------------------------------------------
template<bool ACC>
__global__ __launch_bounds__(256) void gemm_bt_mfma3(
    const unsigned short* __restrict__ Ahi, const unsigned short* __restrict__ Alo,
    const unsigned short* __restrict__ Bhi, const unsigned short* __restrict__ Blo,
    float* __restrict__ C, int M, int Nc, int K)
{
    __shared__ __align__(16) unsigned short sAh[128*32];
    __shared__ __align__(16) unsigned short sAl[128*32];
    __shared__ __align__(16) unsigned short sBh[128*32];
    __shared__ __align__(16) unsigned short sBl[128*32];

    const int tid  = threadIdx.x;
    const int lane = tid & 63;
    const int wave = tid >> 6;
    const int wr = wave >> 1, wc = wave & 1;
    const int brow = blockIdx.y * 128, bcol = blockIdx.x * 128;

    f4v acc[4][4];
#pragma unroll
    for (int i = 0; i < 4; ++i)
#pragma unroll
        for (int j = 0; j < 4; ++j) acc[i][j] = (f4v){0.f, 0.f, 0.f, 0.f};

    const int sr = tid >> 2;
    const int sc = tid & 3;
    const int swz = (sc ^ ((sr >> 1) & 3)) * 8;
    const int wo0 = sr * 32 + swz;
    const int wo1 = wo0 + 64 * 32;

    int ar0 = brow + sr;      if (ar0 >= M) ar0 = 0;
    int ar1 = brow + sr + 64; if (ar1 >= M) ar1 = 0;
    const size_t aoff0 = (size_t)ar0 * K + sc * 8;
    const size_t aoff1 = (size_t)ar1 * K + sc * 8;
    const size_t boff0 = (size_t)(bcol + sr) * K + sc * 8;
    const size_t boff1 = (size_t)(bcol + sr + 64) * K + sc * 8;

    const int g  = lane >> 4;
    const int fr = lane & 15;

    s8v vAh0 = *(const s8v*)(Ahi + aoff0), vAh1 = *(const s8v*)(Ahi + aoff1);
    s8v vAl0 = *(const s8v*)(Alo + aoff0), vAl1 = *(const s8v*)(Alo + aoff1);
    s8v vBh0 = *(const s8v*)(Bhi + boff0), vBh1 = *(const s8v*)(Bhi + boff1);
    s8v vBl0 = *(const s8v*)(Blo + boff0), vBl1 = *(const s8v*)(Blo + boff1);

    for (int kt = 0; kt < K; kt += 32) {
        __syncthreads();
        *(s8v*)(sAh + wo0) = vAh0;  *(s8v*)(sAh + wo1) = vAh1;
        *(s8v*)(sAl + wo0) = vAl0;  *(s8v*)(sAl + wo1) = vAl1;
        *(s8v*)(sBh + wo0) = vBh0;  *(s8v*)(sBh + wo1) = vBh1;
        *(s8v*)(sBl + wo0) = vBl0;  *(s8v*)(sBl + wo1) = vBl1;
        __syncthreads();

        if (kt + 32 < K) {
            int kn = kt + 32;
            vAh0 = *(const s8v*)(Ahi + aoff0 + kn); vAh1 = *(const s8v*)(Ahi + aoff1 + kn);
            vAl0 = *(const s8v*)(Alo + aoff0 + kn); vAl1 = *(const s8v*)(Alo + aoff1 + kn);
            vBh0 = *(const s8v*)(Bhi + boff0 + kn); vBh1 = *(const s8v*)(Bhi + boff1 + kn);
            vBl0 = *(const s8v*)(Blo + boff0 + kn); vBl1 = *(const s8v*)(Blo + boff1 + kn);
        }

        s8v ah[4], al[4], bh[4], bl[4];
#pragma unroll
        for (int mi = 0; mi < 4; ++mi) {
            int row = wr * 64 + mi * 16 + fr;
            int off = row * 32 + ((g ^ ((row >> 1) & 3)) * 8);
            ah[mi] = *(const s8v*)(sAh + off);
            al[mi] = *(const s8v*)(sAl + off);
        }
#pragma unroll
        for (int ni = 0; ni < 4; ++ni) {
            int row = wc * 64 + ni * 16 + fr;
            int off = row * 32 + ((g ^ ((row >> 1) & 3)) * 8);
            bh[ni] = *(const s8v*)(sBh + off);
            bl[ni] = *(const s8v*)(sBl + off);
        }
#pragma unroll
        for (int mi = 0; mi < 4; ++mi)
#pragma unroll
            for (int ni = 0; ni < 4; ++ni) {
                acc[mi][ni] = __builtin_amdgcn_mfma_f32_16x16x32_bf16(ah[mi], bh[ni], acc[mi][ni], 0, 0, 0);
                acc[mi][ni] = __builtin_amdgcn_mfma_f32_16x16x32_bf16(ah[mi], bl[ni], acc[mi][ni], 0, 0, 0);
                acc[mi][ni] = __builtin_amdgcn_mfma_f32_16x16x32_bf16(al[mi], bh[ni], acc[mi][ni], 0, 0, 0);
            }
    }

#pragma unroll
    for (int mi = 0; mi < 4; ++mi) {
#pragma unroll
        for (int v = 0; v < 4; ++v) {
            int row = brow + wr * 64 + mi * 16 + g * 4 + v;
            if (row >= M) continue;
            float* cp = C + (size_t)row * Nc + bcol + wc * 64 + fr;
#pragma unroll
            for (int ni = 0; ni < 4; ++ni) {
                float val = acc[mi][ni][v];
                if (ACC) val += cp[ni * 16];
                cp[ni * 16] = val;
            }
        }
    }
}

// ---------------------------------------------------------------------------
// Plain bf16 MFMA GEMM (LSTM gates): same structure, single hi operand.
// ---------------------------------------------------------------------------
template<bool ACC>
__global__ __launch_bounds__(256) void gemm_bt_mfma1(
    const unsigned short* __restrict__ A,
    const unsigned short* __restrict__ B,
    float* __restrict__ C, int M, int Nc, int K)
{
    __shared__ __align__(16) unsigned short sA[128*32];
    __shared__ __align__(16) unsigned short sB[128*32];

    const int tid  = threadIdx.x;
    const int lane = tid & 63;
    const int wave = tid >> 6;
    const int wr = wave >> 1, wc = wave & 1;
    const int brow = blockIdx.y * 128, bcol = blockIdx.x * 128;

    f4v acc[4][4];
#pragma unroll
    for (int i = 0; i < 4; ++i)
#pragma unroll
        for (int j = 0; j < 4; ++j) acc[i][j] = (f4v){0.f, 0.f, 0.f, 0.f};

    const int sr = tid >> 2;
    const int sc = tid & 3;
    const int swz = (sc ^ ((sr >> 1) & 3)) * 8;
    const int wo0 = sr * 32 + swz;
    const int wo1 = wo0 + 64 * 32;

    int ar0 = brow + sr;      if (ar0 >= M) ar0 = 0;
    int ar1 = brow + sr + 64; if (ar1 >= M) ar1 = 0;
    const size_t aoff0 = (size_t)ar0 * K + sc * 8;
    const size_t aoff1 = (size_t)ar1 * K + sc * 8;
    const size_t boff0 = (size_t)(bcol + sr) * K + sc * 8;
    const size_t boff1 = (size_t)(bcol + sr + 64) * K + sc * 8;

    const int g  = lane >> 4;
    const int fr = lane & 15;

    s8v vA0 = *(const s8v*)(A + aoff0), vA1 = *(const s8v*)(A + aoff1);
    s8v vB0 = *(const s8v*)(B + boff0), vB1 = *(const s8v*)(B + boff1);

    for (int kt = 0; kt < K; kt += 32) {
        __syncthreads();
        *(s8v*)(sA + wo0) = vA0;  *(s8v*)(sA + wo1) = vA1;
        *(s8v*)(sB + wo0) = vB0;  *(s8v*)(sB + wo1) = vB1;
        __syncthreads();

        if (kt + 32 < K) {
            int kn = kt + 32;
            vA0 = *(const s8v*)(A + aoff0 + kn); vA1 = *(const s8v*)(A + aoff1 + kn);
            vB0 = *(const s8v*)(B + boff0 + kn); vB1 = *(const s8v*)(B + boff1 + kn);
        }

        s8v a[4], b[4];
#pragma unroll
        for (int mi = 0; mi < 4; ++mi) {
            int row = wr * 64 + mi * 16 + fr;
            a[mi] = *(const s8v*)(sA + row * 32 + ((g ^ ((row >> 1) & 3)) * 8));
        }
#pragma unroll
        for (int ni = 0; ni < 4; ++ni) {
            int row = wc * 64 + ni * 16 + fr;
            b[ni] = *(const s8v*)(sB + row * 32 + ((g ^ ((row >> 1) & 3)) * 8));
        }
#pragma unroll
        for (int mi = 0; mi < 4; ++mi)
#pragma unroll
            for (int ni = 0; ni < 4; ++ni)
                acc[mi][ni] = __builtin_amdgcn_mfma_f32_16x16x32_bf16(a[mi], b[ni], acc[mi][ni], 0, 0, 0);
    }

#pragma unroll
    for (int mi = 0; mi < 4; ++mi) {
#pragma unroll
        for (int v = 0; v < 4; ++v) {
            int row = brow + wr * 64 + mi * 16 + g * 4 + v;
            if (row >= M) continue;
            float* cp = C + (size_t)row * Nc + bcol + wc * 64 + fr;
#pragma unroll
            for (int ni = 0; ni < 4; ++ni) {
                float val = acc[mi][ni][v];
                if (ACC) val += cp[ni * 16];
                cp[ni * 16] = val;
            }
        }
    }
}

// ---------------------------------------------------------------------------
// CSR build (dest-sorted incoming-edge lists, self loop first in each segment)
// ---------------------------------------------------------------------------
__global__ void deg_init(int* deg, int n) {
    int i = blockIdx.x * blockDim.x + threadIdx.x;
    if (i < n) deg[i] = 1;
}
__global__ void hist_dest(const int* __restrict__ dst, int* deg, int e) {
    for (int i = blockIdx.x * blockDim.x + threadIdx.x; i < e; i += gridDim.x * blockDim.x)
        atomicAdd(&deg[dst[i]], 1);
}
__global__ void scan_excl(const int* __restrict__ deg, int* __restrict__ off, int n) {
    __shared__ int s[1024];
    __shared__ int carry;
    int tid = threadIdx.x;
    if (tid == 0) { carry = 0; off[0] = 0; }
    __syncthreads();
    for (int base = 0; base < n; base += 1024) {
        int i = base + tid;
        s[tid] = (i < n) ? deg[i] : 0;
        __syncthreads();
        for (int st = 1; st < 1024; st <<= 1) {
            int t = (tid >= st) ? s[tid - st] : 0;
            __syncthreads();
            s[tid] += t;
            __syncthreads();
        }
        int incl = s[tid] + carry;
        if (i < n) off[i + 1] = incl;
        __syncthreads();
        if (tid == 1023) carry = incl;
        __syncthreads();
    }
}
__global__ void scatter_self(const int* __restrict__ off, int* cur, int* srcI, int n) {
    int i = blockIdx.x * blockDim.x + threadIdx.x;
    if (i < n) { int p = off[i]; srcI[p] = i; cur[i] = p + 1; }
}
__global__ void scatter_edges(const int* __restrict__ es, const int* __restrict__ ed,
                              int* cur, int* srcI, int e) {
    for (int i = blockIdx.x * blockDim.x + threadIdx.x; i < e; i += gridDim.x * blockDim.x) {
        int p = atomicAdd(&cur[ed[i]], 1);
        srcI[p] = es[i];
    }
}

// ---------------------------------------------------------------------------
// GAT attention coefficients; one wave per node.
// ---------------------------------------------------------------------------
__global__ __launch_bounds__(256) void attn_ab(const float* __restrict__ h,
                                               const float* __restrict__ asrc,
                                               const float* __restrict__ adst,
                                               float* __restrict__ a_s, float* __restrict__ a_d, int n)
{
    int node = blockIdx.x * 4 + (threadIdx.x >> 6);
    if (node >= n) return;
    int lane = threadIdx.x & 63;
    const float* hp = h + (size_t)node * CDIM + lane * 8;
    float4 h0 = *(const float4*)hp, h1 = *(const float4*)(hp + 4);
    float4 w0 = *(const float4*)(asrc + lane * 8);
    float4 w1 = *(const float4*)(asrc + lane * 8 + 4);
    float4 u0 = *(const float4*)(adst + lane * 8);
    float4 u1 = *(const float4*)(adst + lane * 8 + 4);
    float s = h0.x*w0.x + h0.y*w0.y + h0.z*w0.z + h0.w*w0.w
            + h1.x*w1.x + h1.y*w1.y + h1.z*w1.z + h1.w*w1.w;
    float d = h0.x*u0.x + h0.y*u0.y + h0.z*u0.z + h0.w*u0.w
            + h1.x*u1.x + h1.y*u1.y + h1.z*u1.z + h1.w*u1.w;
#pragma unroll
    for (int m = 8; m >= 1; m >>= 1) { s += __shfl_xor(s, m); d += __shfl_xor(d, m); }
    if ((lane & 15) == 0) {
        int head = lane >> 4;
        a_s[node * 4 + head] = s;
        a_d[node * 4 + head] = d;
    }
}

// ---------------------------------------------------------------------------
// GAT aggregate: one wave per dest node; 3 passes (max, exp-sum, gather).
// ---------------------------------------------------------------------------
__global__ __launch_bounds__(256) void gat_agg(const float* __restrict__ h,
                                               const float* __restrict__ a_s,
                                               const float* __restrict__ a_d,
                                               const int* __restrict__ off,
                                               const int* __restrict__ srcI,
                                               const float* __restrict__ bias,
                                               float* __restrict__ out, int n)
{
    int node = blockIdx.x * 4 + (threadIdx.x >> 6);
    if (node >= n) return;
    int lane = threadIdx.x & 63;
    int o0 = off[node], o1 = off[node + 1];
    float4 ad4 = *(const float4*)(a_d + node * 4);
    float ad[4] = {ad4.x, ad4.y, ad4.z, ad4.w};

    float mx[4] = {-3.4e38f, -3.4e38f, -3.4e38f, -3.4e38f};
    for (int e = o0 + lane; e < o1; e += 64) {
        int s = srcI[e];
        float4 as4 = *(const float4*)(a_s + s * 4);
        float as[4] = {as4.x, as4.y, as4.z, as4.w};
#pragma unroll
        for (int hh = 0; hh < 4; ++hh) mx[hh] = fmaxf(mx[hh], lrelu(as[hh] + ad[hh]));
    }
#pragma unroll
    for (int m = 32; m >= 1; m >>= 1)
#pragma unroll
        for (int hh = 0; hh < 4; ++hh) mx[hh] = fmaxf(mx[hh], __shfl_xor(mx[hh], m));

    float den[4] = {0.f, 0.f, 0.f, 0.f};
    for (int e = o0 + lane; e < o1; e += 64) {
        int s = srcI[e];
        float4 as4 = *(const float4*)(a_s + s * 4);
        float as[4] = {as4.x, as4.y, as4.z, as4.w};
#pragma unroll
        for (int hh = 0; hh < 4; ++hh) den[hh] += expf(lrelu(as[hh] + ad[hh]) - mx[hh]);
    }
#pragma unroll
    for (int m = 32; m >= 1; m >>= 1)
#pragma unroll
        for (int hh = 0; hh < 4; ++hh) den[hh] += __shfl_xor(den[hh], m);

    int myh = lane >> 4;
    float admy = ad[myh], mmy = mx[myh], dinv = 1.f / den[myh];
    float acc[8] = {0.f,0.f,0.f,0.f,0.f,0.f,0.f,0.f};
    int e = o0;
    for (; e + 1 < o1; e += 2) {
        int s0 = srcI[e], s1 = srcI[e + 1];
        float al0 = expf(lrelu(a_s[s0 * 4 + myh] + admy) - mmy) * dinv;
        float al1 = expf(lrelu(a_s[s1 * 4 + myh] + admy) - mmy) * dinv;
        const float* hp0 = h + (size_t)s0 * CDIM + lane * 8;
        const float* hp1 = h + (size_t)s1 * CDIM + lane * 8;
        float4 a0 = *(const float4*)hp0, a1 = *(const float4*)(hp0 + 4);
        float4 b0 = *(const float4*)hp1, b1 = *(const float4*)(hp1 + 4);
        acc[0] = fmaf(al0, a0.x, acc[0]); acc[1] = fmaf(al0, a0.y, acc[1]);
        acc[2] = fmaf(al0, a0.z, acc[2]); acc[3] = fmaf(al0, a0.w, acc[3]);
        acc[4] = fmaf(al0, a1.x, acc[4]); acc[5] = fmaf(al0, a1.y, acc[5]);
        acc[6] = fmaf(al0, a1.z, acc[6]); acc[7] = fmaf(al0, a1.w, acc[7]);
        acc[0] = fmaf(al1, b0.x, acc[0]); acc[1] = fmaf(al1, b0.y, acc[1]);
        acc[2] = fmaf(al1, b0.z, acc[2]); acc[3] = fmaf(al1, b0.w, acc[3]);
        acc[4] = fmaf(al1, b1.x, acc[4]); acc[5] = fmaf(al1, b1.y, acc[5]);
        acc[6] = fmaf(al1, b1.z, acc[6]); acc[7] = fmaf(al1, b1.w, acc[7]);
    }
    for (; e < o1; ++e) {
        int s = srcI[e];
        float alpha = expf(lrelu(a_s[s * 4 + myh] + admy) - mmy) * dinv;
        const float* hp = h + (size_t)s * CDIM + lane * 8;
        float4 h0 = *(const float4*)hp, h1 = *(const float4*)(hp + 4);
        acc[0] = fmaf(alpha, h0.x, acc[0]); acc[1] = fmaf(alpha, h0.y, acc[1]);
        acc[2] = fmaf(alpha, h0.z, acc[2]); acc[3] = fmaf(alpha, h0.w, acc[3]);
        acc[4] = fmaf(alpha, h1.x, acc[4]); acc[5] = fmaf(alpha, h1.y, acc[5]);
        acc[6] = fmaf(alpha, h1.z, acc[6]); acc[7] = fmaf(alpha, h1.w, acc[7]);
    }
    const float* bp = bias + lane * 8;
    float4 b0 = *(const float4*)bp, b1 = *(const float4*)(bp + 4);
    float* op = out + (size_t)node * CDIM + lane * 8;
    float4 r0, r1;
    r0.x = fmaxf(acc[0] + b0.x, 0.f); r0.y = fmaxf(acc[1] + b0.y, 0.f);
    r0.z = fmaxf(acc[2] + b0.z, 0.f); r0.w = fmaxf(acc[3] + b0.w, 0.f);
    r1.x = fmaxf(acc[4] + b1.x, 0.f); r1.y = fmaxf(acc[5] + b1.y, 0.f);
    r1.z = fmaxf(acc[6] + b1.z, 0.f); r1.w = fmaxf(acc[7] + b1.w, 0.f);
    *(float4*)op = r0; *(float4*)(op + 4) = r1;
}

// ---------------------------------------------------------------------------
// LSTM pointwise: gates(+biases) -> c update; h emitted as single bf16.
// Fused JK score dot.
// ---------------------------------------------------------------------------
__global__ __launch_bounds__(256) void lstm_pw2(const float* __restrict__ gates,
                                                const float* __restrict__ bih,
                                                const float* __restrict__ bhh,
                                                unsigned short* __restrict__ hb,
                                                float* __restrict__ c,
                                                const float* __restrict__ attw,
                                                float* __restrict__ scoreOut, int first)
{
    int r = blockIdx.x, tid = threadIdx.x;
    const float* gr = gates + (size_t)r * GATE;
    float part = 0.f;
#pragma unroll
    for (int q = 0; q < 3; ++q) {
        int j = tid + q * 256;
        float gi = gr[j]        + bih[j]        + bhh[j];
        float gf = gr[768 + j]  + bih[768 + j]  + bhh[768 + j];
        float gg = gr[1536 + j] + bih[1536 + j] + bhh[1536 + j];
        float go = gr[2304 + j] + bih[2304 + j] + bhh[2304 + j];
        float cold = first ? 0.f : c[(size_t)r * HLDIM + j];
        float cn = sigf(gf) * cold + sigf(gi) * tanhf(gg);
        float hn = sigf(go) * tanhf(cn);
        c[(size_t)r * HLDIM + j] = cn;
        hb[(size_t)r * HLDIM + j] = f2bf(hn);
        part = fmaf(hn, attw[j], part);
    }
    __shared__ float red[256];
    red[tid] = part;
    __syncthreads();
    for (int s = 128; s > 0; s >>= 1) { if (tid < s) red[tid] += red[tid + s]; __syncthreads(); }
    if (tid == 0) scoreOut[r] = red[0];
}

// ---------------------------------------------------------------------------
// JK: per-node 3-way softmax over layer scores, weighted X sum -> xjk [N][512]
// One block per node (memory-bound, high occupancy).
// ---------------------------------------------------------------------------
__global__ __launch_bounds__(256) void jk_xjk(const float* __restrict__ Xall,
                                              const float* __restrict__ scF,
                                              const float* __restrict__ scR,
                                              const float* __restrict__ attbp,
                                              float* __restrict__ xjk, int n)
{
    int node = blockIdx.x, tid = threadIdx.x;
    float attb = *attbp;
    float s0 = scF[node]         + scR[node]         + attb;
    float s1 = scF[n + node]     + scR[n + node]     + attb;
    float s2 = scF[2 * n + node] + scR[2 * n + node] + attb;
    float m = fmaxf(s0, fmaxf(s1, s2));
    float e0 = expf(s0 - m), e1 = expf(s1 - m), e2 = expf(s2 - m);
    float inv = 1.f / (e0 + e1 + e2);
    float a0 = e0 * inv, a1 = e1 * inv, a2 = e2 * inv;
    size_t b  = (size_t)node * CDIM;
    size_t n1 = (size_t)n * CDIM;
#pragma unroll
    for (int q = 0; q < 2; ++q) {
        int col = tid + q * 256;
        xjk[b + col] = a0 * Xall[b + col] + a1 * Xall[n1 + b + col] + a2 * Xall[2 * n1 + b + col];
    }
}

// ---------------------------------------------------------------------------
// Final: per-graph mean pool of xjk, fc1-relu, fc2-relu, fc3.
// ---------------------------------------------------------------------------
__device__ __forceinline__ int lower_bound_i(const int* a, int n, int v) {
    int lo = 0, hi = n;
    while (lo < hi) { int m = (lo + hi) >> 1; if (a[m] < v) lo = m + 1; else hi = m; }
    return lo;
}

__global__ __launch_bounds__(256) void final_pool_mlp2(
    const float* __restrict__ xjk, const int* __restrict__ batch,
    const float* __restrict__ fc1W, const float* __restrict__ fc1b,
    const float* __restrict__ fc2W, const float* __restrict__ fc2b,
    const float* __restrict__ fc3W, const float* __restrict__ fc3b,
    float* __restrict__ out, int n)
{
    __shared__ float bufA[512];
    __shared__ float bufB[512];
    int g = blockIdx.x, tid = threadIdx.x;
    int lo = lower_bound_i(batch, n, g), hi = lower_bound_i(batch, n, g + 1);
    float acc0 = 0.f, acc1 = 0.f;
    for (int nd = lo; nd < hi; ++nd) {
        size_t b = (size_t)nd * CDIM;
        acc0 += xjk[b + tid];
        acc1 += xjk[b + 256 + tid];
    }
    float cinv = 1.f / (float)((hi - lo) > 0 ? (hi - lo) : 1);
    bufA[tid] = acc0 * cinv; bufA[tid + 256] = acc1 * cinv;
    __syncthreads();
    float v0 = 0.f, v1 = 0.f;
#pragma unroll 8
    for (int k = 0; k < 512; ++k) {
        float gk = bufA[k];
        v0 = fmaf(gk, fc1W[k * 512 + tid], v0);
        v1 = fmaf(gk, fc1W[k * 512 + 256 + tid], v1);
    }
    bufB[tid] = fmaxf(v0 + fc1b[tid], 0.f);
    bufB[tid + 256] = fmaxf(v1 + fc1b[tid + 256], 0.f);
    __syncthreads();
    v0 = 0.f; v1 = 0.f;
#pragma unroll 8
    for (int k = 0; k < 512; ++k) {
        float hk = bufB[k];
        v0 = fmaf(hk, fc2W[k * 512 + tid], v0);
        v1 = fmaf(hk, fc2W[k * 512 + 256 + tid], v1);
    }
    bufA[tid] = fmaxf(v0 + fc2b[tid], 0.f);
    bufA[tid + 256] = fmaxf(v1 + fc2b[tid + 256], 0.f);
    __syncthreads();
    int j = tid & 7, k0 = tid >> 3;
    float p = 0.f;
    for (int k = k0; k < 512; k += 32) p = fmaf(bufA[k], fc3W[k * 8 + j], p);
    bufB[tid] = p;
    __syncthreads();
    if (tid < 8) {
        float s = 0.f;
        for (int m = 0; m < 32; ++m) s += bufB[tid + 8 * m];
        out[g * 8 + tid] = s + fc3b[tid];
    }
}

// ---------------------------------------------------------------------------
extern "C" void kernel_launch(void* const* d_in, const int* in_sizes, int n_in,
                              void* d_out, int out_size, void* d_ws, size_t ws_size,
                              hipStream_t stream)
{
    (void)in_sizes; (void)n_in; (void)out_size;
    const float* x     = (const float*)d_in[0];
    const int*   eidx  = (const int*)d_in[1];     // (2,E): row0 = src, row1 = dst
    const int*   batch = (const int*)d_in[2];
    const float* W[3]    = {(const float*)d_in[3],  (const float*)d_in[7],  (const float*)d_in[11]};
    const float* asrc[3] = {(const float*)d_in[4],  (const float*)d_in[8],  (const float*)d_in[12]};
    const float* adst[3] = {(const float*)d_in[5],  (const float*)d_in[9],  (const float*)d_in[13]};
    const float* bgat[3] = {(const float*)d_in[6],  (const float*)d_in[10], (const float*)d_in[14]};
    const float* Wih[2]  = {(const float*)d_in[15], (const float*)d_in[19]};
    const float* Whh[2]  = {(const float*)d_in[16], (const float*)d_in[20]};
    const float* bih[2]  = {(const float*)d_in[17], (const float*)d_in[21]};
    const float* bhh[2]  = {(const float*)d_in[18], (const float*)d_in[22]};
    const float* attw = (const float*)d_in[23];
    const float* attb = (const float*)d_in[24];
    const float* fc1W = (const float*)d_in[25];
    const float* fc1b = (const float*)d_in[26];
    const float* fc2W = (const float*)d_in[27];
    const float* fc2b = (const float*)d_in[28];
    const float* fc3W = (const float*)d_in[29];
    const float* fc3b = (const float*)d_in[30];
    float* out = (float*)d_out;

    // ---- workspace layout (byte allocator, 64B aligned) ----
    char* base = (char*)d_ws;
    size_t off = 0;
    auto alloc = [&](size_t bytes) -> void* {
        off = (off + 63) & ~(size_t)63;
        void* p = base + off; off += bytes; return p;
    };
    float* Xall = (float*)alloc((size_t)3 * N_NODES * CDIM * 4);   // X0|X1|X2
    float* xjk  = (float*)alloc((size_t)N_NODES * CDIM * 4);
    float* cbuf = (float*)alloc((size_t)N_NODES * HLDIM * 4);
    float* a_s  = (float*)alloc((size_t)N_NODES * 4 * 4);
    float* a_d  = (float*)alloc((size_t)N_NODES * 4 * 4);
    float* scF  = (float*)alloc((size_t)3 * N_NODES * 4);
    float* scR  = (float*)alloc((size_t)3 * N_NODES * 4);
    unsigned short* Xhi = (unsigned short*)alloc((size_t)3 * N_NODES * CDIM * 2);
    unsigned short* Xlo = (unsigned short*)alloc((size_t)3 * N_NODES * CDIM * 2);
    unsigned short* xhi = (unsigned short*)alloc((size_t)N_NODES * 128 * 2);
    unsigned short* xlo = (unsigned short*)alloc((size_t)N_NODES * 128 * 2);
    unsigned short* hbf = (unsigned short*)alloc((size_t)N_NODES * HLDIM * 2);
    unsigned short* wtH[3], *wtL[3];
    int wk[3] = {128, 512, 512};
    for (int l = 0; l < 3; ++l) {
        wtH[l] = (unsigned short*)alloc((size_t)CDIM * wk[l] * 2);
        wtL[l] = (unsigned short*)alloc((size_t)CDIM * wk[l] * 2);
    }
    unsigned short* wihB[2], *whhB[2];
    for (int d = 0; d < 2; ++d) {
        wihB[d] = (unsigned short*)alloc((size_t)GATE * CDIM * 2);
        whhB[d] = (unsigned short*)alloc((size_t)GATE * HLDIM * 2);
    }
    int* offI = (int*)alloc((size_t)(N_NODES + 1) * 4);
    int* srcI = (int*)alloc((size_t)(N_EDGES + N_NODES) * 4);
    int* degI = (int*)alloc((size_t)N_NODES * 4);
    off = (off + 63) & ~(size_t)63;
    float* tail = (float*)(base + off);              // time-shared: hproj | gates
    size_t tailF = (ws_size > off) ? (ws_size - off) / 4 : 0;
    float* hproj = tail;
    float* gates = tail;
    int chunkRows = (int)(tailF / GATE);
    if (chunkRows > N_NODES) chunkRows = N_NODES;
    if (chunkRows < 128) chunkRows = 128;

    // ---- CSR by destination (self loop first per segment) ----
    deg_init<<<(N_NODES + 255) / 256, 256, 0, stream>>>(degI, N_NODES);
    hist_dest<<<512, 256, 0, stream>>>(eidx + N_EDGES, degI, N_EDGES);
    scan_excl<<<1, 1024, 0, stream>>>(degI, offI, N_NODES);
    scatter_self<<<(N_NODES + 255) / 256, 256, 0, stream>>>(offI, degI, srcI, N_NODES);
    scatter_edges<<<512, 256, 0, stream>>>(eidx, eidx + N_EDGES, degI, srcI, N_EDGES);

    // ---- weight preprocessing ----
    {
        dim3 tb(32, 8);
        transp_split<<<dim3(CDIM / 32, 128 / 32), tb, 0, stream>>>(W[0], wtH[0], wtL[0], 128, CDIM);
        transp_split<<<dim3(CDIM / 32, 512 / 32), tb, 0, stream>>>(W[1], wtH[1], wtL[1], 512, CDIM);
        transp_split<<<dim3(CDIM / 32, 512 / 32), tb, 0, stream>>>(W[2], wtH[2], wtL[2], 512, CDIM);
        for (int d = 0; d < 2; ++d) {
            int n4i = GATE * CDIM / 4, n4h = GATE * HLDIM / 4;
            cast_bf16<<<(n4i + 255) / 256, 256, 0, stream>>>(Wih[d], wihB[d], n4i);
            cast_bf16<<<(n4h + 255) / 256, 256, 0, stream>>>(Whh[d], whhB[d], n4h);
        }
        int n4x = N_NODES * 128 / 4;
        split_bf16<<<(n4x + 255) / 256, 256, 0, stream>>>(x, xhi, xlo, n4x);
    }

    // ---- GAT layers (bf16x3 MFMA projections, fp32 attention/aggregation) ----
    const unsigned short* inH = xhi;
    const unsigned short* inL = xlo;
    int Kd = 128;
    for (int l = 0; l < 3; ++l) {
        float* Xl = Xall + (size_t)l * N_NODES * CDIM;
        dim3 gg(CDIM / 128, (N_NODES + 127) / 128);
        gemm_bt_mfma3<false><<<gg, 256, 0, stream>>>(inH, inL, wtH[l], wtL[l], hproj,
                                                     N_NODES, CDIM, Kd);
        attn_ab<<<(N_NODES + 3) / 4, 256, 0, stream>>>(hproj, asrc[l], adst[l], a_s, a_d, N_NODES);
        gat_agg<<<(N_NODES + 3) / 4, 256, 0, stream>>>(hproj, a_s, a_d, offI, srcI, bgat[l], Xl, N_NODES);
        int n4 = N_NODES * CDIM / 4;
        split_bf16<<<(n4 + 255) / 256, 256, 0, stream>>>(Xl, Xhi + (size_t)l * N_NODES * CDIM,
                                                         Xlo + (size_t)l * N_NODES * CDIM, n4);
        inH = Xhi + (size_t)l * N_NODES * CDIM;
        inL = Xlo + (size_t)l * N_NODES * CDIM;
        Kd = CDIM;
    }

    // ---- Bidirectional LSTM (seq len 3), plain-bf16 MFMA GEMMs ----
    for (int dir = 0; dir < 2; ++dir) {
        const float* aw = attw + dir * HLDIM;
        float* sc = (dir == 0) ? scF : scR;
        for (int cs = 0; cs < N_NODES; cs += chunkRows) {
            int rows = (N_NODES - cs < chunkRows) ? (N_NODES - cs) : chunkRows;
            dim3 gg(GATE / 128, (rows + 127) / 128);
            for (int t = 0; t < 3; ++t) {
                int l = (dir == 0) ? t : (2 - t);
                size_t xo = ((size_t)l * N_NODES + cs) * CDIM;
                gemm_bt_mfma1<false><<<gg, 256, 0, stream>>>(
                    Xhi + xo, wihB[dir], gates, rows, GATE, CDIM);
                if (t > 0)
                    gemm_bt_mfma1<true><<<gg, 256, 0, stream>>>(
                        hbf + (size_t)cs * HLDIM, whhB[dir], gates, rows, GATE, HLDIM);
                lstm_pw2<<<rows, 256, 0, stream>>>(gates, bih[dir], bhh[dir],
                                                   hbf + (size_t)cs * HLDIM,
                                                   cbuf + (size_t)cs * HLDIM,
                                                   aw, sc + (size_t)l * N_NODES + cs, t == 0 ? 1 : 0);
            }
        }
    }

    // ---- JK weighted sum (per node), then per-graph pool + MLP head ----
    jk_xjk<<<N_NODES, 256, 0, stream>>>(Xall, scF, scR, attb, xjk, N_NODES);
    final_pool_mlp2<<<NGRAPH, 256, 0, stream>>>(xjk, batch, fc1W, fc1b, fc2W, fc2b,
                                                fc3W, fc3b, out, N_NODES);
}